// Round 24
// baseline (126.258 us; speedup 1.0000x reference)
//
#include <hip/hip_runtime.h>
#include <hip/hip_bf16.h>

typedef __attribute__((ext_vector_type(8))) short bf16x8;
typedef __attribute__((ext_vector_type(4))) float f32x4;

#define BATCH 2
#define T_SEQ 2048
#define C_EMB 1024
#define NH 16
#define HS 64

// async 16B global -> LDS (wave-uniform LDS base, + lane*16 implicit)
__device__ __forceinline__ void gld_lds16(const __hip_bfloat16* g, void* l) {
    __builtin_amdgcn_global_load_lds((const __attribute__((address_space(1))) uint32_t*)g,
                                     (__attribute__((address_space(3))) uint32_t*)l, 16, 0, 0);
}

// packed f32x2 -> bf16x2 in one VALU op (no builtin on gfx950 -> inline asm)
__device__ __forceinline__ unsigned pk_bf16(float a, float b) {
    unsigned r;
    asm("v_cvt_pk_bf16_f32 %0, %1, %2" : "=v"(r) : "v"(a), "v"(b));
    return r;   // lo16 = bf16(a), hi16 = bf16(b)
}

// pack 8 f32 (2 float4) -> 8 bf16, store 16B to LDS
__device__ __forceinline__ void pack_store(char* dst, float4 a, float4 b) {
    uint4 u;
    u.x = pk_bf16(a.x, a.y);
    u.y = pk_bf16(a.z, a.w);
    u.z = pk_bf16(b.x, b.y);
    u.w = pk_bf16(b.z, b.w);
    *(uint4*)dst = u;
}

// ---------------- QKV projection GEMM: 256x96 tile, ring-2 LDS, 2 blocks/CU ----
// M=4096, N=3072, K=1024. 512 blocks (16x32), 8 waves (4M x 2N), per-wave 64x48
// (acc[4][3]). Reg-staged fp32->bf16: prefetch depth lives in REGISTERS (2 pend
// sets), so LDS is a ring-2 of half-K buffers: data written at phase p is read
// at p+1; write target = buffer read at p-1 (safe after that barrier).
// LDS = A[2][256x32] 32KB + B[2][96x32] 12KB = 44KB -> 2 blocks resident/CU:
// independent barrier domains cover each other's phase stalls.
#define NT_K 16   // 1024/64

__launch_bounds__(512, 4)
__global__ void qkv_gemm(const float* __restrict__ xf,            // [4096][1024] fp32
                         const float* __restrict__ wf,            // [3072][1024] fp32
                         const float* __restrict__ bias,          // [3072]
                         __hip_bfloat16* __restrict__ qo,         // [BH][T][64] (pre-scaled)
                         __hip_bfloat16* __restrict__ ko,         // [BH][T][64]
                         __hip_bfloat16* __restrict__ vto)        // [BH][64][T]
{
    __shared__ __align__(16) char smem[45056];
    __hip_bfloat16* ASB = (__hip_bfloat16*)smem;              // [2][256*32] = 32KB
    __hip_bfloat16* BSB = (__hip_bfloat16*)(smem + 32768);    // [2][96*32]  = 12KB
    const int nTn = (3 * C_EMB) / 96;    // 32
    int bid = blockIdx.x;
    int wgid = (bid & 7) * 64 + (bid >> 3);   // 512 blocks, bijective XCD swizzle
    int bm = wgid / nTn, bn = wgid % nTn;
    int m0 = bm * 256, n0 = bn * 96;
    int tid  = threadIdx.x;
    int lane = tid & 63, w = tid >> 6;
    int wr = w >> 1, wc = w & 1;                 // 4M x 2N wave grid
    int c = lane & 15, g = lane >> 4;
    int sr = lane >> 2;                          // staging row offset 0..15
    int j  = lane & 3;                           // natural logical 16B chunk
    int pc = j ^ ((sr >> 1) & 3);                // physical chunk (bank swizzle)
    int rchnk = (g ^ ((c >> 1) & 3)) << 4;       // read-side physical chunk (bytes)

#define LOAD_AB(kt, kh, pa_, pb_) { \
    int col_ = (kt) * 64 + (kh) * 32 + j * 8; \
    _Pragma("unroll") for (int i_ = 0; i_ < 2; ++i_) { \
        const float* s_ = &xf[(size_t)(m0 + w * 32 + i_ * 16 + sr) * 1024 + col_]; \
        pa_[2 * i_] = *(const float4*)s_; pa_[2 * i_ + 1] = *(const float4*)(s_ + 4); } \
    if (w < 6) { \
        const float* s_ = &wf[(size_t)(n0 + w * 16 + sr) * 1024 + col_]; \
        pb_[0] = *(const float4*)s_; pb_[1] = *(const float4*)(s_ + 4); } }

#define WRITE_AB(buf_, pa_, pb_) { \
    _Pragma("unroll") for (int i_ = 0; i_ < 2; ++i_) \
        pack_store((char*)&ASB[(buf_) * 8192 + (w * 32 + i_ * 16 + sr) * 32 + pc * 8], \
                   pa_[2 * i_], pa_[2 * i_ + 1]); \
    if (w < 6) \
        pack_store((char*)&BSB[(buf_) * 3072 + (w * 16 + sr) * 32 + pc * 8], \
                   pb_[0], pb_[1]); }

    f32x4 acc[4][3];
#pragma unroll
    for (int mi = 0; mi < 4; ++mi)
#pragma unroll
        for (int ni = 0; ni < 3; ++ni)
            acc[mi][ni] = (f32x4){0.f, 0.f, 0.f, 0.f};

    float4 s0a[4], s1a[4];
    float4 s0b[2], s1b[2];
    bool v_s0 = false, v_s1 = false;

    // ---- prologue: data(ph0) -> buf0 directly; s1 = data(ph1) pend ----
    LOAD_AB(0, 0, s0a, s0b); WRITE_AB(0, s0a, s0b);
    LOAD_AB(0, 1, s1a, s1b); v_s1 = true;
    __syncthreads();

    for (int t = 0; t < NT_K; ++t) {
#pragma unroll
        for (int ks = 0; ks < 2; ++ks) {
            const __hip_bfloat16* AL = &ASB[ks * 8192];
            const __hip_bfloat16* BL = &BSB[ks * 3072];
            bf16x8 bfr[3], af[4];
#pragma unroll
            for (int ni = 0; ni < 3; ++ni)
                bfr[ni] = *(const bf16x8*)((const char*)BL + (wc * 48 + ni * 16 + c) * 64 + rchnk);
#pragma unroll
            for (int mi = 0; mi < 4; ++mi)
                af[mi] = *(const bf16x8*)((const char*)AL + (wr * 64 + mi * 16 + c) * 64 + rchnk);
            // ---- issue fp32 loads for phase p+2 ----
            if (ks == 0) {
                if (t + 1 < NT_K) { LOAD_AB(t + 1, 0, s0a, s0b); v_s0 = true; }
                else v_s0 = false;
            } else {
                if (t + 1 < NT_K) { LOAD_AB(t + 1, 1, s1a, s1b); v_s1 = true; }
                else v_s1 = false;
            }
            // ---- MFMA cluster ----
            __builtin_amdgcn_s_setprio(1);
#pragma unroll
            for (int mi = 0; mi < 4; ++mi)
#pragma unroll
                for (int ni = 0; ni < 3; ++ni)
                    acc[mi][ni] = __builtin_amdgcn_mfma_f32_16x16x32_bf16(af[mi], bfr[ni], acc[mi][ni], 0, 0, 0);
            __builtin_amdgcn_s_setprio(0);
            // ---- write the pend set loaded LAST phase into the other buffer ----
            if (ks == 0) { if (v_s1) WRITE_AB(1, s1a, s1b); }   // data(t, k1) -> buf1
            else         { if (v_s0) WRITE_AB(0, s0a, s0b); }   // data(t+1, k0) -> buf0
            asm volatile("s_waitcnt lgkmcnt(0)" ::: "memory");  // ds_writes visible
            __builtin_amdgcn_s_barrier();
        }
    }
#undef LOAD_AB
#undef WRITE_AB

    // ---- epilogue: per-frag routing (each 16-col frag is section-pure) ----
    const float QSCALE = 0.125f * 1.44269504088896340736f;  // HS^-0.5 * log2(e)
    __syncthreads();                    // reclaim staging LDS for V scratch
    int b = m0 >> 11;
    int t0 = (m0 & (T_SEQ - 1)) + wr * 64;
#pragma unroll
    for (int ni = 0; ni < 3; ++ni) {
        int nb = n0 + wc * 48 + ni * 16;     // frag base column
        int s = nb >> 10;
        int h = (nb >> 6) & (NH - 1);
        float bv = bias[nb + c];
        if (s < 2) {
            __hip_bfloat16* dst = (s == 0) ? qo : ko;
            float scale = (s == 0) ? QSCALE : 1.0f;
            int dd = (nb & 63) + c;
            size_t bhb = (size_t)(b * NH + h) * T_SEQ;
#pragma unroll
            for (int mi = 0; mi < 4; ++mi) {
#pragma unroll
                for (int r = 0; r < 4; ++r) {
                    int tt = t0 + mi * 16 + g * 4 + r;
                    dst[(bhb + tt) * HS + dd] = __float2bfloat16((acc[mi][ni][r] + bv) * scale);
                }
            }
        } else {
            // V frag: transpose 64t x 16d through per-wave serial 2KB scratch
            int dbase = nb & 63;
            char* scr = smem + w * 2048;     // reused serially across ni (wave-local)
#pragma unroll
            for (int mi = 0; mi < 4; ++mi) {
#pragma unroll
                for (int r = 0; r < 4; ++r) {
                    int m = mi * 16 + g * 4 + r;       // 0..63 (t within frag)
                    __hip_bfloat16 hv = __float2bfloat16(acc[mi][ni][r] + bv);
                    *(ushort*)(scr + c * 128 + ((((m >> 3) ^ (c & 7)) & 7) << 4) + (m & 7) * 2) = *(ushort*)&hv;
                }
            }
            size_t bhv = (size_t)(b * NH + h);
            int d_lo = lane >> 3, tch = lane & 7;
#pragma unroll
            for (int p = 0; p < 2; ++p) {
                int d = p * 8 + d_lo;                  // d within frag 0..15
                bf16x8 vv = *(bf16x8*)(scr + d * 128 + (((tch ^ (d & 7)) & 7) << 4));
                *(bf16x8*)(&vto[(bhv * HS + dbase + d) * T_SEQ + t0 + tch * 8]) = vv;
            }
        }
    }
}

// ---------------- causal flash attention (R19/R20/R23 version — best measured) ----
__launch_bounds__(256, 4)
__global__ void attn_fwd(const __hip_bfloat16* __restrict__ qb,   // [BH][T][64], *0.125*log2e
                         const __hip_bfloat16* __restrict__ kb,   // [BH][T][64]
                         const __hip_bfloat16* __restrict__ vtb,  // [BH][64][T]
                         float* __restrict__ out)                 // [B][T][C]
{
    __shared__ __align__(16) char smem[40960];

    int idx = blockIdx.x;
    int bh = idx & 31;
    int qt = 31 - (idx >> 5);            // big q-tiles dispatched first
    int w  = threadIdx.x >> 6;           // wave 0..3
    int lane = threadIdx.x & 63;
    int c = lane & 15, g = lane >> 4;
    char* p_strip = smem + 32768 + w * 2048;

    const __hip_bfloat16* Qp = qb  + (size_t)bh * T_SEQ * HS;
    const __hip_bfloat16* Kp = kb  + (size_t)bh * T_SEQ * HS;
    const __hip_bfloat16* Vp = vtb + (size_t)bh * HS * T_SEQ;
    int b = bh >> 4, h = bh & (NH - 1);

    int srow = lane >> 3;
    int scol = ((lane & 7) ^ srow) << 3;     // pre-swizzled source col (elems)
    int swz  = (c & 7) << 4;                 // K/V read-side XOR (bytes)
    int krow0 = w * 16 + srow;
    int krow1 = w * 16 + 8 + srow;
    int qw = qt * 64 + w * 16;
    int ntile = qt + 1;

    bf16x8 qf[2];
    qf[0] = *(const bf16x8*)(&Qp[(size_t)(qw + c) * HS + g * 8]);
    qf[1] = *(const bf16x8*)(&Qp[(size_t)(qw + c) * HS + 32 + g * 8]);

    f32x4 oacc[4];
#pragma unroll
    for (int i = 0; i < 4; ++i) oacc[i] = (f32x4){0.f, 0.f, 0.f, 0.f};
    float lrow = 0.f;

#define ATT_STAGE(t_, buf_) { \
    int k0_ = (t_) * 64; \
    char* kb_ = smem + (buf_) * 8192; \
    char* vb_ = smem + 16384 + (buf_) * 8192; \
    gld_lds16(&Kp[(size_t)(k0_ + krow0) * HS + scol],  kb_ + (w * 16) * 128); \
    gld_lds16(&Kp[(size_t)(k0_ + krow1) * HS + scol],  kb_ + (w * 16 + 8) * 128); \
    gld_lds16(&Vp[(size_t)krow0 * T_SEQ + k0_ + scol], vb_ + (w * 16) * 128); \
    gld_lds16(&Vp[(size_t)krow1 * T_SEQ + k0_ + scol], vb_ + (w * 16 + 8) * 128); }

    ATT_STAGE(0, 0);

    for (int tix = 0; tix < ntile; ++tix) {
        int cur = tix & 1;
        asm volatile("s_waitcnt vmcnt(0)" ::: "memory");
        __builtin_amdgcn_s_barrier();
        if (tix + 1 < ntile) ATT_STAGE(tix + 1, cur ^ 1);

        bool diag = (tix == ntile - 1);
        const char* KL = smem + cur * 8192;
        const char* VL = smem + 16384 + cur * 8192;

        f32x4 sacc[4];
#pragma unroll
        for (int i = 0; i < 4; ++i) sacc[i] = (f32x4){0.f, 0.f, 0.f, 0.f};
        __builtin_amdgcn_s_setprio(1);
#pragma unroll
        for (int ks = 0; ks < 2; ++ks)
#pragma unroll
            for (int kc = 0; kc < 4; ++kc)
                if (!diag || kc <= w) {
                    int rr = kc * 16 + c;
                    int colB = (ks * 64 + g * 16) ^ swz;
                    bf16x8 kf = *(const bf16x8*)(KL + rr * 128 + colB);
                    sacc[kc] = __builtin_amdgcn_mfma_f32_16x16x32_bf16(kf, qf[ks], sacc[kc], 0, 0, 0);
                }
        __builtin_amdgcn_s_setprio(0);

        // ---- P = exp2(S), lane-local sum, v_cvt_pk_bf16_f32 pack, 8B writes ----
#pragma unroll
        for (int kc = 0; kc < 4; ++kc) {
            float p0, p1, p2, p3;
            if (!diag) {
                p0 = __builtin_amdgcn_exp2f(sacc[kc][0]);
                p1 = __builtin_amdgcn_exp2f(sacc[kc][1]);
                p2 = __builtin_amdgcn_exp2f(sacc[kc][2]);
                p3 = __builtin_amdgcn_exp2f(sacc[kc][3]);
            } else {
                int kbase = kc * 16 + g * 4;
                int lim = w * 16 + c;
                p0 = (kc <= w && kbase + 0 <= lim) ? __builtin_amdgcn_exp2f(sacc[kc][0]) : 0.f;
                p1 = (kc <= w && kbase + 1 <= lim) ? __builtin_amdgcn_exp2f(sacc[kc][1]) : 0.f;
                p2 = (kc <= w && kbase + 2 <= lim) ? __builtin_amdgcn_exp2f(sacc[kc][2]) : 0.f;
                p3 = (kc <= w && kbase + 3 <= lim) ? __builtin_amdgcn_exp2f(sacc[kc][3]) : 0.f;
            }
            lrow += (p0 + p1) + (p2 + p3);
            unsigned lo = pk_bf16(p0, p1);
            unsigned hi = pk_bf16(p2, p3);
            int gran = ((kc * 2 + (g >> 1)) ^ (c & 7)) << 4;
            *(uint2*)(p_strip + c * 128 + gran + ((g & 1) << 3)) = make_uint2(lo, hi);
        }

        int ksm = diag ? ((w >= 2) ? 2 : 1) : 2;
        __builtin_amdgcn_s_setprio(1);
#pragma unroll
        for (int ks = 0; ks < 2; ++ks) {
            if (ks >= ksm) break;
            int pgran = ((ks * 4 + g) ^ (c & 7)) << 4;
            bf16x8 pf = *(bf16x8*)(p_strip + c * 128 + pgran);
#pragma unroll
            for (int d16 = 0; d16 < 4; ++d16) {
                int dr = d16 * 16 + c;
                int colB = (ks * 64 + g * 16) ^ swz;
                bf16x8 vf = *(const bf16x8*)(VL + dr * 128 + colB);
                oacc[d16] = __builtin_amdgcn_mfma_f32_16x16x32_bf16(vf, pf, oacc[d16], 0, 0, 0);
            }
        }
        __builtin_amdgcn_s_setprio(0);
    }

    float v = lrow;
    v += __shfl_xor(v, 16, 64);
    v += __shfl_xor(v, 32, 64);
    float linv = 1.0f / v;
    float* orow = &out[((size_t)(b * T_SEQ + qw + c)) * C_EMB + h * HS + g * 4];
#pragma unroll
    for (int d16 = 0; d16 < 4; ++d16) {
        float4 st;
        st.x = oacc[d16][0] * linv;
        st.y = oacc[d16][1] * linv;
        st.z = oacc[d16][2] * linv;
        st.w = oacc[d16][3] * linv;
        *(float4*)(&orow[d16 * 16]) = st;
    }
#undef ATT_STAGE
}

// ---------------- launch ----------------
extern "C" void kernel_launch(void* const* d_in, const int* in_sizes, int n_in,
                              void* d_out, int out_size, void* d_ws, size_t ws_size,
                              hipStream_t stream) {
    const float* x    = (const float*)d_in[0];   // [2][2048][1024]
    const float* W    = (const float*)d_in[1];   // [3072][1024]
    const float* bias = (const float*)d_in[2];   // [3072]
    float* out = (float*)d_out;

    char* ws = (char*)d_ws;
    __hip_bfloat16* qo  = (__hip_bfloat16*)(ws + (14u << 20));        // 8 MB
    __hip_bfloat16* ko  = (__hip_bfloat16*)(ws + (22u << 20));        // 8 MB
    __hip_bfloat16* vto = (__hip_bfloat16*)(ws + (30u << 20));        // 8 MB

    int gemm_grid = (BATCH * T_SEQ / 256) * (3 * C_EMB / 96);  // 16*32 = 512
    qkv_gemm<<<gemm_grid, 512, 0, stream>>>(x, W, bias, qo, ko, vto);

    attn_fwd<<<1024, 256, 0, stream>>>(qo, ko, vto, out);
}

// Round 25
// 72.071 us; speedup vs baseline: 1.7518x; 1.7518x over previous
//
#include <hip/hip_runtime.h>
#include <hip/hip_bf16.h>

typedef __attribute__((ext_vector_type(8))) short bf16x8;
typedef __attribute__((ext_vector_type(4))) float f32x4;

#define BATCH 2
#define T_SEQ 2048
#define C_EMB 1024
#define NH 16
#define HS 64

// async 16B global -> LDS (wave-uniform LDS base, + lane*16 implicit)
__device__ __forceinline__ void gld_lds16(const __hip_bfloat16* g, void* l) {
    __builtin_amdgcn_global_load_lds((const __attribute__((address_space(1))) uint32_t*)g,
                                     (__attribute__((address_space(3))) uint32_t*)l, 16, 0, 0);
}

// packed f32x2 -> bf16x2 in one VALU op (no builtin on gfx950 -> inline asm)
__device__ __forceinline__ unsigned pk_bf16(float a, float b) {
    unsigned r;
    asm("v_cvt_pk_bf16_f32 %0, %1, %2" : "=v"(r) : "v"(a), "v"(b));
    return r;   // lo16 = bf16(a), hi16 = bf16(b)
}

// pack 8 f32 (2 float4) -> 8 bf16, store 16B to LDS
__device__ __forceinline__ void pack_store(char* dst, float4 a, float4 b) {
    uint4 u;
    u.x = pk_bf16(a.x, a.y);
    u.y = pk_bf16(a.z, a.w);
    u.z = pk_bf16(b.x, b.y);
    u.w = pk_bf16(b.z, b.w);
    *(uint4*)dst = u;
}

// ---------------- QKV projection GEMM: fused fp32 staging, 4Mx2N waves (R23 best) ----
// M=4096, N=3072, K=1024. 256 blocks (16x16), 8 waves 4M x 2N (per-wave 64x96,
// acc[4][6]). Reg-staged fp32->bf16: float4 loads 3 phases ahead; one phase
// later: pack (v_cvt_pk_bf16_f32) -> swizzled ds_write_b128. 2 barriers/K-tile.
#define NT_K 16   // 1024/64

__launch_bounds__(512, 2)
__global__ void qkv_gemm(const float* __restrict__ xf,            // [4096][1024] fp32
                         const float* __restrict__ wf,            // [3072][1024] fp32
                         const float* __restrict__ bias,          // [3072]
                         __hip_bfloat16* __restrict__ qo,         // [BH][T][64] (pre-scaled)
                         __hip_bfloat16* __restrict__ ko,         // [BH][T][64]
                         __hip_bfloat16* __restrict__ vto)        // [BH][64][T]
{
    __shared__ __align__(16) char smem[114688];
    __hip_bfloat16* ASB = (__hip_bfloat16*)smem;              // [4][256*32] = 64KB
    __hip_bfloat16* BSB = (__hip_bfloat16*)(smem + 65536);    // [4][192*32] = 48KB
    const int nTn = (3 * C_EMB) / 192;   // 16
    int bid = blockIdx.x;
    int wgid = (bid & 7) * 32 + (bid >> 3);   // 256 blocks, bijective XCD swizzle
    int bm = wgid / nTn, bn = wgid % nTn;
    int m0 = bm * 256, n0 = bn * 192;
    int tid  = threadIdx.x;
    int lane = tid & 63, w = tid >> 6;
    int wr = w >> 1, wc = w & 1;                 // 4M x 2N wave grid
    int c = lane & 15, g = lane >> 4;
    int sr = lane >> 2;                          // staging row offset 0..15
    int j  = lane & 3;                           // natural logical 16B chunk
    int pc = j ^ ((sr >> 1) & 3);                // physical chunk (bank swizzle)
    int rchnk = (g ^ ((c >> 1) & 3)) << 4;       // read-side physical chunk (bytes)

#define LOAD_AB(kt, kh, pa_, pb_) { \
    int col_ = (kt) * 64 + (kh) * 32 + j * 8; \
    _Pragma("unroll") for (int i_ = 0; i_ < 2; ++i_) { \
        const float* s_ = &xf[(size_t)(m0 + w * 32 + i_ * 16 + sr) * 1024 + col_]; \
        pa_[2 * i_] = *(const float4*)s_; pa_[2 * i_ + 1] = *(const float4*)(s_ + 4); } \
    if (w < 4) { \
        _Pragma("unroll") for (int i_ = 0; i_ < 2; ++i_) { \
            const float* s_ = &wf[(size_t)(n0 + w * 32 + i_ * 16 + sr) * 1024 + col_]; \
            pb_[2 * i_] = *(const float4*)s_; pb_[2 * i_ + 1] = *(const float4*)(s_ + 4); } \
    } else { \
        const float* s_ = &wf[(size_t)(n0 + 128 + (w - 4) * 16 + sr) * 1024 + col_]; \
        pb_[0] = *(const float4*)s_; pb_[1] = *(const float4*)(s_ + 4); } }

#define WRITE_AB(tb_, pa_, pb_) { \
    _Pragma("unroll") for (int i_ = 0; i_ < 2; ++i_) \
        pack_store((char*)&ASB[(tb_) * 8192 + (w * 32 + i_ * 16 + sr) * 32 + pc * 8], \
                   pa_[2 * i_], pa_[2 * i_ + 1]); \
    if (w < 4) { \
        _Pragma("unroll") for (int i_ = 0; i_ < 2; ++i_) \
            pack_store((char*)&BSB[(tb_) * 6144 + (w * 32 + i_ * 16 + sr) * 32 + pc * 8], \
                       pb_[2 * i_], pb_[2 * i_ + 1]); \
    } else { \
        pack_store((char*)&BSB[(tb_) * 6144 + (128 + (w - 4) * 16 + sr) * 32 + pc * 8], \
                   pb_[0], pb_[1]); } }

    f32x4 acc[4][6];
#pragma unroll
    for (int mi = 0; mi < 4; ++mi)
#pragma unroll
        for (int ni = 0; ni < 6; ++ni)
            acc[mi][ni] = (f32x4){0.f, 0.f, 0.f, 0.f};

    float4 s0a[4], s0b[4], s1a[4], s1b[4];
    int tb_s0 = 0, tb_s1 = 0;
    bool v_s0 = false, v_s1 = false;

    // ---- prologue: stage (0,k0),(0,k1) directly; S1 = loads for (1,k0) ----
    LOAD_AB(0, 0, s0a, s0b); WRITE_AB(0, s0a, s0b);
    LOAD_AB(0, 1, s0a, s0b); WRITE_AB(1, s0a, s0b);
    LOAD_AB(1, 0, s1a, s1b); tb_s1 = 2; v_s1 = true;
    __syncthreads();

    for (int t = 0; t < NT_K; ++t) {
        int buf = t & 1;
#pragma unroll
        for (int ks = 0; ks < 2; ++ks) {
            const __hip_bfloat16* AL = &ASB[(buf * 2 + ks) * 8192];
            const __hip_bfloat16* BL = &BSB[(buf * 2 + ks) * 6144];
            bf16x8 bfr[6], af[4];
#pragma unroll
            for (int ni = 0; ni < 6; ++ni)
                bfr[ni] = *(const bf16x8*)((const char*)BL + (wc * 96 + ni * 16 + c) * 64 + rchnk);
#pragma unroll
            for (int mi = 0; mi < 4; ++mi)
                af[mi] = *(const bf16x8*)((const char*)AL + (wr * 64 + mi * 16 + c) * 64 + rchnk);
            // ---- issue fp32 loads for the buffer 3 phases ahead ----
            if (ks == 0) {
                if (t + 1 < NT_K) { LOAD_AB(t + 1, 1, s0a, s0b); tb_s0 = ((t + 1) & 1) * 2 + 1; v_s0 = true; }
                else v_s0 = false;
            } else {
                if (t + 2 < NT_K) { LOAD_AB(t + 2, 0, s1a, s1b); tb_s1 = ((t + 2) & 1) * 2; v_s1 = true; }
                else v_s1 = false;
            }
            // ---- MFMA cluster ----
            __builtin_amdgcn_s_setprio(1);
#pragma unroll
            for (int mi = 0; mi < 4; ++mi)
#pragma unroll
                for (int ni = 0; ni < 6; ++ni)
                    acc[mi][ni] = __builtin_amdgcn_mfma_f32_16x16x32_bf16(af[mi], bfr[ni], acc[mi][ni], 0, 0, 0);
            __builtin_amdgcn_s_setprio(0);
            // ---- pack+write the set issued LAST phase (counted vmcnt by compiler) ----
            if (ks == 0) { if (v_s1) WRITE_AB(tb_s1, s1a, s1b); }
            else         { if (v_s0) WRITE_AB(tb_s0, s0a, s0b); }
            asm volatile("s_waitcnt lgkmcnt(0)" ::: "memory");   // ds_writes visible
            __builtin_amdgcn_s_barrier();
        }
    }
#undef LOAD_AB
#undef WRITE_AB

    // ---- epilogue: per-frag routing (each 16-col frag is section-pure) ----
    const float QSCALE = 0.125f * 1.44269504088896340736f;  // HS^-0.5 * log2(e)
    __syncthreads();                    // reclaim staging LDS for V scratch
    int b = m0 >> 11;
    int t0 = (m0 & (T_SEQ - 1)) + wr * 64;
#pragma unroll
    for (int ni = 0; ni < 6; ++ni) {
        int nb = n0 + wc * 96 + ni * 16;     // frag base column
        int s = nb >> 10;
        int h = (nb >> 6) & (NH - 1);
        float bv = bias[nb + c];
        if (s < 2) {
            __hip_bfloat16* dst = (s == 0) ? qo : ko;
            float scale = (s == 0) ? QSCALE : 1.0f;
            int dd = (nb & 63) + c;
            size_t bhb = (size_t)(b * NH + h) * T_SEQ;
#pragma unroll
            for (int mi = 0; mi < 4; ++mi) {
#pragma unroll
                for (int r = 0; r < 4; ++r) {
                    int tt = t0 + mi * 16 + g * 4 + r;
                    dst[(bhb + tt) * HS + dd] = __float2bfloat16((acc[mi][ni][r] + bv) * scale);
                }
            }
        } else {
            // V frag: transpose 64t x 16d through private 2KB scratch -> 16B stores
            int dbase = nb & 63;
            char* scr = smem + (w * 6 + ni) * 2048;   // 48 x 2KB = 96KB <= 112KB
#pragma unroll
            for (int mi = 0; mi < 4; ++mi) {
#pragma unroll
                for (int r = 0; r < 4; ++r) {
                    int m = mi * 16 + g * 4 + r;       // 0..63 (t within frag)
                    __hip_bfloat16 hv = __float2bfloat16(acc[mi][ni][r] + bv);
                    *(ushort*)(scr + c * 128 + ((((m >> 3) ^ (c & 7)) & 7) << 4) + (m & 7) * 2) = *(ushort*)&hv;
                }
            }
            size_t bhv = (size_t)(b * NH + h);
            int d_lo = lane >> 3, tch = lane & 7;
#pragma unroll
            for (int p = 0; p < 2; ++p) {
                int d = p * 8 + d_lo;                  // d within frag 0..15
                bf16x8 vv = *(bf16x8*)(scr + d * 128 + (((tch ^ (d & 7)) & 7) << 4));
                *(bf16x8*)(&vto[(bhv * HS + dbase + d) * T_SEQ + t0 + tch * 8]) = vv;
            }
        }
    }
}

// ---------------- causal flash attention (R19/R20/R23 version — best measured) ----
__launch_bounds__(256, 4)
__global__ void attn_fwd(const __hip_bfloat16* __restrict__ qb,   // [BH][T][64], *0.125*log2e
                         const __hip_bfloat16* __restrict__ kb,   // [BH][T][64]
                         const __hip_bfloat16* __restrict__ vtb,  // [BH][64][T]
                         float* __restrict__ out)                 // [B][T][C]
{
    __shared__ __align__(16) char smem[40960];

    int idx = blockIdx.x;
    int bh = idx & 31;
    int qt = 31 - (idx >> 5);            // big q-tiles dispatched first
    int w  = threadIdx.x >> 6;           // wave 0..3
    int lane = threadIdx.x & 63;
    int c = lane & 15, g = lane >> 4;
    char* p_strip = smem + 32768 + w * 2048;

    const __hip_bfloat16* Qp = qb  + (size_t)bh * T_SEQ * HS;
    const __hip_bfloat16* Kp = kb  + (size_t)bh * T_SEQ * HS;
    const __hip_bfloat16* Vp = vtb + (size_t)bh * HS * T_SEQ;
    int b = bh >> 4, h = bh & (NH - 1);

    int srow = lane >> 3;
    int scol = ((lane & 7) ^ srow) << 3;     // pre-swizzled source col (elems)
    int swz  = (c & 7) << 4;                 // K/V read-side XOR (bytes)
    int krow0 = w * 16 + srow;
    int krow1 = w * 16 + 8 + srow;
    int qw = qt * 64 + w * 16;
    int ntile = qt + 1;

    bf16x8 qf[2];
    qf[0] = *(const bf16x8*)(&Qp[(size_t)(qw + c) * HS + g * 8]);
    qf[1] = *(const bf16x8*)(&Qp[(size_t)(qw + c) * HS + 32 + g * 8]);

    f32x4 oacc[4];
#pragma unroll
    for (int i = 0; i < 4; ++i) oacc[i] = (f32x4){0.f, 0.f, 0.f, 0.f};
    float lrow = 0.f;

#define ATT_STAGE(t_, buf_) { \
    int k0_ = (t_) * 64; \
    char* kb_ = smem + (buf_) * 8192; \
    char* vb_ = smem + 16384 + (buf_) * 8192; \
    gld_lds16(&Kp[(size_t)(k0_ + krow0) * HS + scol],  kb_ + (w * 16) * 128); \
    gld_lds16(&Kp[(size_t)(k0_ + krow1) * HS + scol],  kb_ + (w * 16 + 8) * 128); \
    gld_lds16(&Vp[(size_t)krow0 * T_SEQ + k0_ + scol], vb_ + (w * 16) * 128); \
    gld_lds16(&Vp[(size_t)krow1 * T_SEQ + k0_ + scol], vb_ + (w * 16 + 8) * 128); }

    ATT_STAGE(0, 0);

    for (int tix = 0; tix < ntile; ++tix) {
        int cur = tix & 1;
        asm volatile("s_waitcnt vmcnt(0)" ::: "memory");
        __builtin_amdgcn_s_barrier();
        if (tix + 1 < ntile) ATT_STAGE(tix + 1, cur ^ 1);

        bool diag = (tix == ntile - 1);
        const char* KL = smem + cur * 8192;
        const char* VL = smem + 16384 + cur * 8192;

        f32x4 sacc[4];
#pragma unroll
        for (int i = 0; i < 4; ++i) sacc[i] = (f32x4){0.f, 0.f, 0.f, 0.f};
        __builtin_amdgcn_s_setprio(1);
#pragma unroll
        for (int ks = 0; ks < 2; ++ks)
#pragma unroll
            for (int kc = 0; kc < 4; ++kc)
                if (!diag || kc <= w) {
                    int rr = kc * 16 + c;
                    int colB = (ks * 64 + g * 16) ^ swz;
                    bf16x8 kf = *(const bf16x8*)(KL + rr * 128 + colB);
                    sacc[kc] = __builtin_amdgcn_mfma_f32_16x16x32_bf16(kf, qf[ks], sacc[kc], 0, 0, 0);
                }
        __builtin_amdgcn_s_setprio(0);

        // ---- P = exp2(S), lane-local sum, v_cvt_pk_bf16_f32 pack, 8B writes ----
#pragma unroll
        for (int kc = 0; kc < 4; ++kc) {
            float p0, p1, p2, p3;
            if (!diag) {
                p0 = __builtin_amdgcn_exp2f(sacc[kc][0]);
                p1 = __builtin_amdgcn_exp2f(sacc[kc][1]);
                p2 = __builtin_amdgcn_exp2f(sacc[kc][2]);
                p3 = __builtin_amdgcn_exp2f(sacc[kc][3]);
            } else {
                int kbase = kc * 16 + g * 4;
                int lim = w * 16 + c;
                p0 = (kc <= w && kbase + 0 <= lim) ? __builtin_amdgcn_exp2f(sacc[kc][0]) : 0.f;
                p1 = (kc <= w && kbase + 1 <= lim) ? __builtin_amdgcn_exp2f(sacc[kc][1]) : 0.f;
                p2 = (kc <= w && kbase + 2 <= lim) ? __builtin_amdgcn_exp2f(sacc[kc][2]) : 0.f;
                p3 = (kc <= w && kbase + 3 <= lim) ? __builtin_amdgcn_exp2f(sacc[kc][3]) : 0.f;
            }
            lrow += (p0 + p1) + (p2 + p3);
            unsigned lo = pk_bf16(p0, p1);
            unsigned hi = pk_bf16(p2, p3);
            int gran = ((kc * 2 + (g >> 1)) ^ (c & 7)) << 4;
            *(uint2*)(p_strip + c * 128 + gran + ((g & 1) << 3)) = make_uint2(lo, hi);
        }

        int ksm = diag ? ((w >= 2) ? 2 : 1) : 2;
        __builtin_amdgcn_s_setprio(1);
#pragma unroll
        for (int ks = 0; ks < 2; ++ks) {
            if (ks >= ksm) break;
            int pgran = ((ks * 4 + g) ^ (c & 7)) << 4;
            bf16x8 pf = *(bf16x8*)(p_strip + c * 128 + pgran);
#pragma unroll
            for (int d16 = 0; d16 < 4; ++d16) {
                int dr = d16 * 16 + c;
                int colB = (ks * 64 + g * 16) ^ swz;
                bf16x8 vf = *(const bf16x8*)(VL + dr * 128 + colB);
                oacc[d16] = __builtin_amdgcn_mfma_f32_16x16x32_bf16(vf, pf, oacc[d16], 0, 0, 0);
            }
        }
        __builtin_amdgcn_s_setprio(0);
    }

    float v = lrow;
    v += __shfl_xor(v, 16, 64);
    v += __shfl_xor(v, 32, 64);
    float linv = 1.0f / v;
    float* orow = &out[((size_t)(b * T_SEQ + qw + c)) * C_EMB + h * HS + g * 4];
#pragma unroll
    for (int d16 = 0; d16 < 4; ++d16) {
        float4 st;
        st.x = oacc[d16][0] * linv;
        st.y = oacc[d16][1] * linv;
        st.z = oacc[d16][2] * linv;
        st.w = oacc[d16][3] * linv;
        *(float4*)(&orow[d16 * 16]) = st;
    }
#undef ATT_STAGE
}

// ---------------- launch ----------------
extern "C" void kernel_launch(void* const* d_in, const int* in_sizes, int n_in,
                              void* d_out, int out_size, void* d_ws, size_t ws_size,
                              hipStream_t stream) {
    const float* x    = (const float*)d_in[0];   // [2][2048][1024]
    const float* W    = (const float*)d_in[1];   // [3072][1024]
    const float* bias = (const float*)d_in[2];   // [3072]
    float* out = (float*)d_out;

    char* ws = (char*)d_ws;
    __hip_bfloat16* qo  = (__hip_bfloat16*)(ws + (14u << 20));        // 8 MB
    __hip_bfloat16* ko  = (__hip_bfloat16*)(ws + (22u << 20));        // 8 MB
    __hip_bfloat16* vto = (__hip_bfloat16*)(ws + (30u << 20));        // 8 MB

    int gemm_grid = (BATCH * T_SEQ / 256) * (3 * C_EMB / 192);  // 16*16 = 256
    qkv_gemm<<<gemm_grid, 512, 0, stream>>>(x, W, bias, qo, ko, vto);

    attn_fwd<<<1024, 256, 0, stream>>>(qo, ko, vto, out);
}

// Round 26
// 71.284 us; speedup vs baseline: 1.7712x; 1.0111x over previous
//
#include <hip/hip_runtime.h>
#include <hip/hip_bf16.h>

typedef __attribute__((ext_vector_type(8))) short bf16x8;
typedef __attribute__((ext_vector_type(4))) float f32x4;

#define BATCH 2
#define T_SEQ 2048
#define C_EMB 1024
#define NH 16
#define HS 64

// async 16B global -> LDS (wave-uniform LDS base, + lane*16 implicit)
__device__ __forceinline__ void gld_lds16(const __hip_bfloat16* g, void* l) {
    __builtin_amdgcn_global_load_lds((const __attribute__((address_space(1))) uint32_t*)g,
                                     (__attribute__((address_space(3))) uint32_t*)l, 16, 0, 0);
}

// packed f32x2 -> bf16x2 in one VALU op (no builtin on gfx950 -> inline asm)
__device__ __forceinline__ unsigned pk_bf16(float a, float b) {
    unsigned r;
    asm("v_cvt_pk_bf16_f32 %0, %1, %2" : "=v"(r) : "v"(a), "v"(b));
    return r;   // lo16 = bf16(a), hi16 = bf16(b)
}

// pack 8 f32 (2 float4) -> 8 bf16, store 16B to LDS
__device__ __forceinline__ void pack_store(char* dst, float4 a, float4 b) {
    uint4 u;
    u.x = pk_bf16(a.x, a.y);
    u.y = pk_bf16(a.z, a.w);
    u.z = pk_bf16(b.x, b.y);
    u.w = pk_bf16(b.z, b.w);
    *(uint4*)dst = u;
}

// ---------------- QKV projection GEMM: fused fp32 staging, 4Mx2N waves (best) ----
// M=4096, N=3072, K=1024. 256 blocks (16x16), 8 waves 4M x 2N (per-wave 64x96,
// acc[4][6]). Reg-staged fp32->bf16: float4 loads 3 phases ahead; one phase
// later: pack (v_cvt_pk_bf16_f32) -> swizzled ds_write_b128. 2 barriers/K-tile.
#define NT_K 16   // 1024/64

__launch_bounds__(512, 2)
__global__ void qkv_gemm(const float* __restrict__ xf,            // [4096][1024] fp32
                         const float* __restrict__ wf,            // [3072][1024] fp32
                         const float* __restrict__ bias,          // [3072]
                         __hip_bfloat16* __restrict__ qo,         // [BH][T][64] (pre-scaled)
                         __hip_bfloat16* __restrict__ ko,         // [BH][T][64]
                         __hip_bfloat16* __restrict__ vto)        // [BH][64][T]
{
    __shared__ __align__(16) char smem[114688];
    __hip_bfloat16* ASB = (__hip_bfloat16*)smem;              // [4][256*32] = 64KB
    __hip_bfloat16* BSB = (__hip_bfloat16*)(smem + 65536);    // [4][192*32] = 48KB
    const int nTn = (3 * C_EMB) / 192;   // 16
    int bid = blockIdx.x;
    int wgid = (bid & 7) * 32 + (bid >> 3);   // 256 blocks, bijective XCD swizzle
    int bm = wgid / nTn, bn = wgid % nTn;
    int m0 = bm * 256, n0 = bn * 192;
    int tid  = threadIdx.x;
    int lane = tid & 63, w = tid >> 6;
    int wr = w >> 1, wc = w & 1;                 // 4M x 2N wave grid
    int c = lane & 15, g = lane >> 4;
    int sr = lane >> 2;                          // staging row offset 0..15
    int j  = lane & 3;                           // natural logical 16B chunk
    int pc = j ^ ((sr >> 1) & 3);                // physical chunk (bank swizzle)
    int rchnk = (g ^ ((c >> 1) & 3)) << 4;       // read-side physical chunk (bytes)

#define LOAD_AB(kt, kh, pa_, pb_) { \
    int col_ = (kt) * 64 + (kh) * 32 + j * 8; \
    _Pragma("unroll") for (int i_ = 0; i_ < 2; ++i_) { \
        const float* s_ = &xf[(size_t)(m0 + w * 32 + i_ * 16 + sr) * 1024 + col_]; \
        pa_[2 * i_] = *(const float4*)s_; pa_[2 * i_ + 1] = *(const float4*)(s_ + 4); } \
    if (w < 4) { \
        _Pragma("unroll") for (int i_ = 0; i_ < 2; ++i_) { \
            const float* s_ = &wf[(size_t)(n0 + w * 32 + i_ * 16 + sr) * 1024 + col_]; \
            pb_[2 * i_] = *(const float4*)s_; pb_[2 * i_ + 1] = *(const float4*)(s_ + 4); } \
    } else { \
        const float* s_ = &wf[(size_t)(n0 + 128 + (w - 4) * 16 + sr) * 1024 + col_]; \
        pb_[0] = *(const float4*)s_; pb_[1] = *(const float4*)(s_ + 4); } }

#define WRITE_AB(tb_, pa_, pb_) { \
    _Pragma("unroll") for (int i_ = 0; i_ < 2; ++i_) \
        pack_store((char*)&ASB[(tb_) * 8192 + (w * 32 + i_ * 16 + sr) * 32 + pc * 8], \
                   pa_[2 * i_], pa_[2 * i_ + 1]); \
    if (w < 4) { \
        _Pragma("unroll") for (int i_ = 0; i_ < 2; ++i_) \
            pack_store((char*)&BSB[(tb_) * 6144 + (w * 32 + i_ * 16 + sr) * 32 + pc * 8], \
                       pb_[2 * i_], pb_[2 * i_ + 1]); \
    } else { \
        pack_store((char*)&BSB[(tb_) * 6144 + (128 + (w - 4) * 16 + sr) * 32 + pc * 8], \
                   pb_[0], pb_[1]); } }

    f32x4 acc[4][6];
#pragma unroll
    for (int mi = 0; mi < 4; ++mi)
#pragma unroll
        for (int ni = 0; ni < 6; ++ni)
            acc[mi][ni] = (f32x4){0.f, 0.f, 0.f, 0.f};

    float4 s0a[4], s0b[4], s1a[4], s1b[4];
    int tb_s0 = 0, tb_s1 = 0;
    bool v_s0 = false, v_s1 = false;

    // ---- prologue: stage (0,k0),(0,k1) directly; S1 = loads for (1,k0) ----
    LOAD_AB(0, 0, s0a, s0b); WRITE_AB(0, s0a, s0b);
    LOAD_AB(0, 1, s0a, s0b); WRITE_AB(1, s0a, s0b);
    LOAD_AB(1, 0, s1a, s1b); tb_s1 = 2; v_s1 = true;
    __syncthreads();

    for (int t = 0; t < NT_K; ++t) {
        int buf = t & 1;
#pragma unroll
        for (int ks = 0; ks < 2; ++ks) {
            const __hip_bfloat16* AL = &ASB[(buf * 2 + ks) * 8192];
            const __hip_bfloat16* BL = &BSB[(buf * 2 + ks) * 6144];
            bf16x8 bfr[6], af[4];
#pragma unroll
            for (int ni = 0; ni < 6; ++ni)
                bfr[ni] = *(const bf16x8*)((const char*)BL + (wc * 96 + ni * 16 + c) * 64 + rchnk);
#pragma unroll
            for (int mi = 0; mi < 4; ++mi)
                af[mi] = *(const bf16x8*)((const char*)AL + (wr * 64 + mi * 16 + c) * 64 + rchnk);
            // ---- issue fp32 loads for the buffer 3 phases ahead ----
            if (ks == 0) {
                if (t + 1 < NT_K) { LOAD_AB(t + 1, 1, s0a, s0b); tb_s0 = ((t + 1) & 1) * 2 + 1; v_s0 = true; }
                else v_s0 = false;
            } else {
                if (t + 2 < NT_K) { LOAD_AB(t + 2, 0, s1a, s1b); tb_s1 = ((t + 2) & 1) * 2; v_s1 = true; }
                else v_s1 = false;
            }
            // ---- MFMA cluster ----
            __builtin_amdgcn_s_setprio(1);
#pragma unroll
            for (int mi = 0; mi < 4; ++mi)
#pragma unroll
                for (int ni = 0; ni < 6; ++ni)
                    acc[mi][ni] = __builtin_amdgcn_mfma_f32_16x16x32_bf16(af[mi], bfr[ni], acc[mi][ni], 0, 0, 0);
            __builtin_amdgcn_s_setprio(0);
            // ---- pack+write the set issued LAST phase (counted vmcnt by compiler) ----
            if (ks == 0) { if (v_s1) WRITE_AB(tb_s1, s1a, s1b); }
            else         { if (v_s0) WRITE_AB(tb_s0, s0a, s0b); }
            asm volatile("s_waitcnt lgkmcnt(0)" ::: "memory");   // ds_writes visible
            __builtin_amdgcn_s_barrier();
        }
    }
#undef LOAD_AB
#undef WRITE_AB

    // ---- epilogue: per-frag routing (each 16-col frag is section-pure) ----
    const float QSCALE = 0.125f * 1.44269504088896340736f;  // HS^-0.5 * log2(e)
    __syncthreads();                    // reclaim staging LDS for V scratch
    int b = m0 >> 11;
    int t0 = (m0 & (T_SEQ - 1)) + wr * 64;
#pragma unroll
    for (int ni = 0; ni < 6; ++ni) {
        int nb = n0 + wc * 96 + ni * 16;     // frag base column
        int s = nb >> 10;
        int h = (nb >> 6) & (NH - 1);
        float bv = bias[nb + c];
        if (s < 2) {
            __hip_bfloat16* dst = (s == 0) ? qo : ko;
            float scale = (s == 0) ? QSCALE : 1.0f;
            int dd = (nb & 63) + c;
            size_t bhb = (size_t)(b * NH + h) * T_SEQ;
#pragma unroll
            for (int mi = 0; mi < 4; ++mi) {
#pragma unroll
                for (int r = 0; r < 4; ++r) {
                    int tt = t0 + mi * 16 + g * 4 + r;
                    dst[(bhb + tt) * HS + dd] = __float2bfloat16((acc[mi][ni][r] + bv) * scale);
                }
            }
        } else {
            // V frag: transpose 64t x 16d through private 2KB scratch -> 16B stores
            int dbase = nb & 63;
            char* scr = smem + (w * 6 + ni) * 2048;   // 48 x 2KB = 96KB <= 112KB
#pragma unroll
            for (int mi = 0; mi < 4; ++mi) {
#pragma unroll
                for (int r = 0; r < 4; ++r) {
                    int m = mi * 16 + g * 4 + r;       // 0..63 (t within frag)
                    __hip_bfloat16 hv = __float2bfloat16(acc[mi][ni][r] + bv);
                    *(ushort*)(scr + c * 128 + ((((m >> 3) ^ (c & 7)) & 7) << 4) + (m & 7) * 2) = *(ushort*)&hv;
                }
            }
            size_t bhv = (size_t)(b * NH + h);
            int d_lo = lane >> 3, tch = lane & 7;
#pragma unroll
            for (int p = 0; p < 2; ++p) {
                int d = p * 8 + d_lo;                  // d within frag 0..15
                bf16x8 vv = *(bf16x8*)(scr + d * 128 + (((tch ^ (d & 7)) & 7) << 4));
                *(bf16x8*)(&vto[(bhv * HS + dbase + d) * T_SEQ + t0 + tch * 8]) = vv;
            }
        }
    }
}

// ---------------- causal flash attention (best measured) ----------------
__launch_bounds__(256, 4)
__global__ void attn_fwd(const __hip_bfloat16* __restrict__ qb,   // [BH][T][64], *0.125*log2e
                         const __hip_bfloat16* __restrict__ kb,   // [BH][T][64]
                         const __hip_bfloat16* __restrict__ vtb,  // [BH][64][T]
                         float* __restrict__ out)                 // [B][T][C]
{
    __shared__ __align__(16) char smem[40960];

    int idx = blockIdx.x;
    int bh = idx & 31;
    int qt = 31 - (idx >> 5);            // big q-tiles dispatched first
    int w  = threadIdx.x >> 6;           // wave 0..3
    int lane = threadIdx.x & 63;
    int c = lane & 15, g = lane >> 4;
    char* p_strip = smem + 32768 + w * 2048;

    const __hip_bfloat16* Qp = qb  + (size_t)bh * T_SEQ * HS;
    const __hip_bfloat16* Kp = kb  + (size_t)bh * T_SEQ * HS;
    const __hip_bfloat16* Vp = vtb + (size_t)bh * HS * T_SEQ;
    int b = bh >> 4, h = bh & (NH - 1);

    int srow = lane >> 3;
    int scol = ((lane & 7) ^ srow) << 3;     // pre-swizzled source col (elems)
    int swz  = (c & 7) << 4;                 // K/V read-side XOR (bytes)
    int krow0 = w * 16 + srow;
    int krow1 = w * 16 + 8 + srow;
    int qw = qt * 64 + w * 16;
    int ntile = qt + 1;

    bf16x8 qf[2];
    qf[0] = *(const bf16x8*)(&Qp[(size_t)(qw + c) * HS + g * 8]);
    qf[1] = *(const bf16x8*)(&Qp[(size_t)(qw + c) * HS + 32 + g * 8]);

    f32x4 oacc[4];
#pragma unroll
    for (int i = 0; i < 4; ++i) oacc[i] = (f32x4){0.f, 0.f, 0.f, 0.f};
    float lrow = 0.f;

#define ATT_STAGE(t_, buf_) { \
    int k0_ = (t_) * 64; \
    char* kb_ = smem + (buf_) * 8192; \
    char* vb_ = smem + 16384 + (buf_) * 8192; \
    gld_lds16(&Kp[(size_t)(k0_ + krow0) * HS + scol],  kb_ + (w * 16) * 128); \
    gld_lds16(&Kp[(size_t)(k0_ + krow1) * HS + scol],  kb_ + (w * 16 + 8) * 128); \
    gld_lds16(&Vp[(size_t)krow0 * T_SEQ + k0_ + scol], vb_ + (w * 16) * 128); \
    gld_lds16(&Vp[(size_t)krow1 * T_SEQ + k0_ + scol], vb_ + (w * 16 + 8) * 128); }

    ATT_STAGE(0, 0);

    for (int tix = 0; tix < ntile; ++tix) {
        int cur = tix & 1;
        asm volatile("s_waitcnt vmcnt(0)" ::: "memory");
        __builtin_amdgcn_s_barrier();
        if (tix + 1 < ntile) ATT_STAGE(tix + 1, cur ^ 1);

        bool diag = (tix == ntile - 1);
        const char* KL = smem + cur * 8192;
        const char* VL = smem + 16384 + cur * 8192;

        f32x4 sacc[4];
#pragma unroll
        for (int i = 0; i < 4; ++i) sacc[i] = (f32x4){0.f, 0.f, 0.f, 0.f};
        __builtin_amdgcn_s_setprio(1);
#pragma unroll
        for (int ks = 0; ks < 2; ++ks)
#pragma unroll
            for (int kc = 0; kc < 4; ++kc)
                if (!diag || kc <= w) {
                    int rr = kc * 16 + c;
                    int colB = (ks * 64 + g * 16) ^ swz;
                    bf16x8 kf = *(const bf16x8*)(KL + rr * 128 + colB);
                    sacc[kc] = __builtin_amdgcn_mfma_f32_16x16x32_bf16(kf, qf[ks], sacc[kc], 0, 0, 0);
                }
        __builtin_amdgcn_s_setprio(0);

        // ---- P = exp2(S), lane-local sum, v_cvt_pk_bf16_f32 pack, 8B writes ----
#pragma unroll
        for (int kc = 0; kc < 4; ++kc) {
            float p0, p1, p2, p3;
            if (!diag) {
                p0 = __builtin_amdgcn_exp2f(sacc[kc][0]);
                p1 = __builtin_amdgcn_exp2f(sacc[kc][1]);
                p2 = __builtin_amdgcn_exp2f(sacc[kc][2]);
                p3 = __builtin_amdgcn_exp2f(sacc[kc][3]);
            } else {
                int kbase = kc * 16 + g * 4;
                int lim = w * 16 + c;
                p0 = (kc <= w && kbase + 0 <= lim) ? __builtin_amdgcn_exp2f(sacc[kc][0]) : 0.f;
                p1 = (kc <= w && kbase + 1 <= lim) ? __builtin_amdgcn_exp2f(sacc[kc][1]) : 0.f;
                p2 = (kc <= w && kbase + 2 <= lim) ? __builtin_amdgcn_exp2f(sacc[kc][2]) : 0.f;
                p3 = (kc <= w && kbase + 3 <= lim) ? __builtin_amdgcn_exp2f(sacc[kc][3]) : 0.f;
            }
            lrow += (p0 + p1) + (p2 + p3);
            unsigned lo = pk_bf16(p0, p1);
            unsigned hi = pk_bf16(p2, p3);
            int gran = ((kc * 2 + (g >> 1)) ^ (c & 7)) << 4;
            *(uint2*)(p_strip + c * 128 + gran + ((g & 1) << 3)) = make_uint2(lo, hi);
        }

        int ksm = diag ? ((w >= 2) ? 2 : 1) : 2;
        __builtin_amdgcn_s_setprio(1);
#pragma unroll
        for (int ks = 0; ks < 2; ++ks) {
            if (ks >= ksm) break;
            int pgran = ((ks * 4 + g) ^ (c & 7)) << 4;
            bf16x8 pf = *(bf16x8*)(p_strip + c * 128 + pgran);
#pragma unroll
            for (int d16 = 0; d16 < 4; ++d16) {
                int dr = d16 * 16 + c;
                int colB = (ks * 64 + g * 16) ^ swz;
                bf16x8 vf = *(const bf16x8*)(VL + dr * 128 + colB);
                oacc[d16] = __builtin_amdgcn_mfma_f32_16x16x32_bf16(vf, pf, oacc[d16], 0, 0, 0);
            }
        }
        __builtin_amdgcn_s_setprio(0);
    }

    float v = lrow;
    v += __shfl_xor(v, 16, 64);
    v += __shfl_xor(v, 32, 64);
    float linv = 1.0f / v;
    float* orow = &out[((size_t)(b * T_SEQ + qw + c)) * C_EMB + h * HS + g * 4];
#pragma unroll
    for (int d16 = 0; d16 < 4; ++d16) {
        float4 st;
        st.x = oacc[d16][0] * linv;
        st.y = oacc[d16][1] * linv;
        st.z = oacc[d16][2] * linv;
        st.w = oacc[d16][3] * linv;
        *(float4*)(&orow[d16 * 16]) = st;
    }
#undef ATT_STAGE
}

// ---------------- launch ----------------
extern "C" void kernel_launch(void* const* d_in, const int* in_sizes, int n_in,
                              void* d_out, int out_size, void* d_ws, size_t ws_size,
                              hipStream_t stream) {
    const float* x    = (const float*)d_in[0];   // [2][2048][1024]
    const float* W    = (const float*)d_in[1];   // [3072][1024]
    const float* bias = (const float*)d_in[2];   // [3072]
    float* out = (float*)d_out;

    char* ws = (char*)d_ws;
    __hip_bfloat16* qo  = (__hip_bfloat16*)(ws + (14u << 20));        // 8 MB
    __hip_bfloat16* ko  = (__hip_bfloat16*)(ws + (22u << 20));        // 8 MB
    __hip_bfloat16* vto = (__hip_bfloat16*)(ws + (30u << 20));        // 8 MB

    int gemm_grid = (BATCH * T_SEQ / 256) * (3 * C_EMB / 192);  // 16*16 = 256
    qkv_gemm<<<gemm_grid, 512, 0, stream>>>(x, W, bias, qo, ko, vto);

    attn_fwd<<<1024, 256, 0, stream>>>(qo, ko, vto, out);
}